// Round 1
// baseline (805.582 us; speedup 1.0000x reference)
//
#include <hip/hip_runtime.h>

// GMF scoring: out[x][b][i] = sum_k u[users[b]][k] * w_x[k] * v[i][k]
// x in {view, cart, buy}; B=1024, I=50000, K=64. fp32 in/out.
//
// Structure (v2): write-BW-bound on 614 MB of output. Key change vs v1:
//  - No per-chunk __syncthreads: u fragments are gathered straight from
//    global (L2-resident 262 KB) into registers, converted with HW
//    v_cvt_pk_bf16_f32. The old ut-LDS handoff forced a full vmcnt(0)
//    store drain at every chunk barrier (32x per block), serializing the
//    store stream with compute.
//  - MFMA operands swapped: D[m=item][n=user], so each lane owns 4
//    consecutive items of one user row -> one float4 store (6 dwordx4
//    per chunk instead of 24 scalar dwords), loop-invariant pointers.

#define NUM_ITEMS 50000
#define NUM_B     1024
#define DIMK      64
#define ITILE     64               // items per block
#define UC        32               // users per chunk
#define NCHUNK    (NUM_B / UC)     // 32
#define VPAD      72               // padded LDS row (bf16 elems)

typedef __bf16 bfrag_t __attribute__((ext_vector_type(8)));
typedef float  facc_t  __attribute__((ext_vector_type(4)));

__device__ __forceinline__ unsigned short f2bf(float f) {
    union { float f; unsigned u; } a; a.f = f;
    unsigned r = a.u + 0x7fffu + ((a.u >> 16) & 1u);   // RNE; inputs are small normals
    return (unsigned short)(r >> 16);
}

// 8x f32 -> bf16x8; compiler emits v_cvt_pk_bf16_f32 pairs (RNE, matches f2bf)
__device__ __forceinline__ bfrag_t cvt8(float4 a, float4 b) {
    bfrag_t r;
    r[0] = (__bf16)a.x; r[1] = (__bf16)a.y; r[2] = (__bf16)a.z; r[3] = (__bf16)a.w;
    r[4] = (__bf16)b.x; r[5] = (__bf16)b.y; r[6] = (__bf16)b.z; r[7] = (__bf16)b.w;
    return r;
}

__global__ __launch_bounds__(256) void gmf_kernel(
    const int*   __restrict__ users,   // [1024] gather indices
    const int*   __restrict__ items,   // [50000] (arange, but honored)
    const float* __restrict__ utab,    // [100000][64]
    const float* __restrict__ vtab,    // [50000][64]
    const float* __restrict__ wv,      // [64]
    const float* __restrict__ wc,      // [64]
    const float* __restrict__ wb,      // [64]
    float*       __restrict__ out)     // [3][1024][50000]
{
    __shared__ unsigned short vt[3][ITILE * VPAD];  // v * w_x, bf16 bits

    const int t    = threadIdx.x;
    const int wave = t >> 6;
    const int lane = t & 63;
    const int quad = lane >> 4;
    const int l16  = lane & 15;
    const int iblk = blockIdx.x * ITILE;

    // ---- stage v tile, pre-scaled by each weight (fp32 math, one bf16 rounding) ----
    #pragma unroll
    for (int c = 0; c < 4; ++c) {
        int idx = t + 256 * c;          // 0..1023 = 64 items x 16 float4-chunks
        int it  = idx >> 4;
        int f4  = idx & 15;
        int gi  = iblk + it;
        float4 v = make_float4(0.f, 0.f, 0.f, 0.f);
        if (gi < NUM_ITEMS) {
            int row = items[gi];
            v = *(const float4*)(vtab + row * DIMK + f4 * 4);
        }
        float4 w0 = *(const float4*)(wv + f4 * 4);
        float4 w1 = *(const float4*)(wc + f4 * 4);
        float4 w2 = *(const float4*)(wb + f4 * 4);
        ushort4 s;
        s.x = f2bf(v.x * w0.x); s.y = f2bf(v.y * w0.y);
        s.z = f2bf(v.z * w0.z); s.w = f2bf(v.w * w0.w);
        *(ushort4*)(&vt[0][it * VPAD + f4 * 4]) = s;
        s.x = f2bf(v.x * w1.x); s.y = f2bf(v.y * w1.y);
        s.z = f2bf(v.z * w1.z); s.w = f2bf(v.w * w1.w);
        *(ushort4*)(&vt[1][it * VPAD + f4 * 4]) = s;
        s.x = f2bf(v.x * w2.x); s.y = f2bf(v.y * w2.y);
        s.z = f2bf(v.z * w2.z); s.w = f2bf(v.w * w2.w);
        *(ushort4*)(&vt[2][it * VPAD + f4 * 4]) = s;
    }
    __syncthreads();   // the ONLY barrier in the kernel

    // ---- v fragments in registers: A-operand (m = item = l16, k = quad*8+j) ----
    bfrag_t vfx[3][2];
    #pragma unroll
    for (int x = 0; x < 3; ++x) {
        const unsigned short* vr = &vt[x][(wave * 16 + l16) * VPAD + quad * 8];
        vfx[x][0] = *(const bfrag_t*)(vr);
        vfx[x][1] = *(const bfrag_t*)(vr + 32);
    }
    // LDS is read-only from here on; no further barriers, stores never drain.

    // D layout (operands swapped): col(n) = l16 = user, row(m) = quad*4 + r = item.
    // Each lane stores a contiguous float4 of 4 items for one user row.
    const int  icol   = iblk + wave * 16 + quad * 4;
    const bool istore = (icol < NUM_ITEMS);    // 50000 % 4 == 0 -> all-or-nothing per lane

    float* p[3][2];
    #pragma unroll
    for (int x = 0; x < 3; ++x)
        #pragma unroll
        for (int s = 0; s < 2; ++s)
            p[x][s] = out + ((long)x * NUM_B + s * 16 + l16) * (long)NUM_ITEMS + icol;

    const float* ubase = utab + quad * 8;

    // B-operand gather: lane l16 needs u[users[base + l16]][quad*8 .. +7] and [+32 .. +39]
    auto loadu = [&](int uc, float4* r) {
        #pragma unroll
        for (int s = 0; s < 2; ++s) {
            int row = users[uc * UC + s * 16 + l16];
            const float* up = ubase + (long)row * DIMK;
            r[s * 4 + 0] = *(const float4*)(up + 0);
            r[s * 4 + 1] = *(const float4*)(up + 4);
            r[s * 4 + 2] = *(const float4*)(up + 32);
            r[s * 4 + 3] = *(const float4*)(up + 36);
        }
    };

    auto compute = [&](const float4* r) {
        bfrag_t a[2][2];
        #pragma unroll
        for (int s = 0; s < 2; ++s) {
            a[s][0] = cvt8(r[s * 4 + 0], r[s * 4 + 1]);
            a[s][1] = cvt8(r[s * 4 + 2], r[s * 4 + 3]);
        }
        facc_t acc[2][3];
        #pragma unroll
        for (int s = 0; s < 2; ++s)
            #pragma unroll
            for (int x = 0; x < 3; ++x)
                acc[s][x] = (facc_t){0.f, 0.f, 0.f, 0.f};
        #pragma unroll
        for (int s = 0; s < 2; ++s)
            #pragma unroll
            for (int x = 0; x < 3; ++x) {
                acc[s][x] = __builtin_amdgcn_mfma_f32_16x16x32_bf16(vfx[x][0], a[s][0], acc[s][x], 0, 0, 0);
                acc[s][x] = __builtin_amdgcn_mfma_f32_16x16x32_bf16(vfx[x][1], a[s][1], acc[s][x], 0, 0, 0);
            }
        if (istore) {
            #pragma unroll
            for (int x = 0; x < 3; ++x)
                #pragma unroll
                for (int s = 0; s < 2; ++s)
                    *(facc_t*)p[x][s] = acc[s][x];
        }
        #pragma unroll
        for (int x = 0; x < 3; ++x)
            #pragma unroll
            for (int s = 0; s < 2; ++s)
                p[x][s] += (long)UC * NUM_ITEMS;
    };

    // 1-deep software pipeline: next chunk's u gathers fly under current MFMAs.
    float4 raw[8];
    loadu(0, raw);
    #pragma unroll 4
    for (int uc = 0; uc < NCHUNK - 1; ++uc) {
        float4 nxt[8];
        loadu(uc + 1, nxt);
        compute(raw);
        #pragma unroll
        for (int i = 0; i < 8; ++i) raw[i] = nxt[i];
    }
    compute(raw);
}

extern "C" void kernel_launch(void* const* d_in, const int* in_sizes, int n_in,
                              void* d_out, int out_size, void* d_ws, size_t ws_size,
                              hipStream_t stream) {
    const int*   users = (const int*)  d_in[0];   // batch_users [1024]
    const int*   items = (const int*)  d_in[1];   // whole_items [50000]
    // d_in[2] = dropout_ration (0) -> identity, ignored
    const float* utab  = (const float*)d_in[3];   // user_table [100000][64]
    const float* vtab  = (const float*)d_in[4];   // item_table [50000][64]
    const float* wv    = (const float*)d_in[5];   // weight_view [64]
    const float* wc    = (const float*)d_in[6];   // weight_cart [64]
    const float* wb    = (const float*)d_in[7];   // weight_buy [64]
    float* out = (float*)d_out;                   // [3][1024][50000]

    const int grid = (NUM_ITEMS + ITILE - 1) / ITILE;   // 782
    gmf_kernel<<<grid, 256, 0, stream>>>(users, items, utab, vtab, wv, wc, wb, out);
}

// Round 2
// 703.958 us; speedup vs baseline: 1.1444x; 1.1444x over previous
//
#include <hip/hip_runtime.h>

// GMF scoring: out[x][b][i] = sum_k u[users[b]][k] * w_x[k] * v[i][k]
// x in {view, cart, buy}; B=1024, I=50000, K=64. fp32 in/out.
//
// v3 structure: v1's cooperative coalesced staging + LDS broadcast (low VGPR,
// 0 bank conflicts), with the store-drain removed:
//  - ut double-buffered; per-chunk sync is raw s_barrier + s_waitcnt lgkmcnt(0)
//    ONLY. __syncthreads (vmcnt(0) drain) would flush the output-store stream
//    32x per block; lgkmcnt-only lets stores stay in flight for the whole
//    kernel. The only cross-thread hazard is the LDS ut buffer (lgkm-tracked).
//  - MFMA operands swapped: D[m=item][n=user] -> each lane stores one
//    contiguous float4 (6 dwordx4/chunk instead of 24 scalar stores).
//  - Non-temporal stores: 614 MB write-once output must not evict the
//    L2-resident u/v tables.

#define NUM_ITEMS 50000
#define NUM_B     1024
#define DIMK      64
#define ITILE     64               // items per block
#define UC        32               // users per chunk
#define NCHUNK    (NUM_B / UC)     // 32
#define VPAD      72               // padded LDS row (bf16 elems): 144 B stride
#define UPAD      72

typedef __bf16 bfrag_t __attribute__((ext_vector_type(8)));
typedef float  facc_t  __attribute__((ext_vector_type(4)));

__device__ __forceinline__ unsigned short f2bf(float f) {
    union { float f; unsigned u; } a; a.f = f;
    unsigned r = a.u + 0x7fffu + ((a.u >> 16) & 1u);   // RNE; inputs are small normals
    return (unsigned short)(r >> 16);
}

__global__ __launch_bounds__(256) void gmf_kernel(
    const int*   __restrict__ users,   // [1024] gather indices
    const int*   __restrict__ items,   // [50000] (arange, but honored)
    const float* __restrict__ utab,    // [100000][64]
    const float* __restrict__ vtab,    // [50000][64]
    const float* __restrict__ wv,      // [64]
    const float* __restrict__ wc,      // [64]
    const float* __restrict__ wb,      // [64]
    float*       __restrict__ out)     // [3][1024][50000]
{
    __shared__ unsigned short vt[3][ITILE * VPAD];  // v * w_x, bf16 bits
    __shared__ unsigned short ut[2][UC * UPAD];     // gathered u, bf16 bits, dbuf

    const int t    = threadIdx.x;
    const int wave = t >> 6;
    const int lane = t & 63;
    const int quad = lane >> 4;
    const int l16  = lane & 15;
    const int iblk = blockIdx.x * ITILE;

    const int us = t >> 4;    // 0..15: user slot within chunk (this thread + slot+16)
    const int f4 = t & 15;    // float4 column within the 64-float row

    // ---- stage v tile, pre-scaled by each weight (fp32 math, one bf16 rounding) ----
    #pragma unroll
    for (int c = 0; c < 4; ++c) {
        int idx = t + 256 * c;          // 0..1023 = 64 items x 16 float4-chunks
        int it  = idx >> 4;
        int fc  = idx & 15;
        int gi  = iblk + it;
        float4 v = make_float4(0.f, 0.f, 0.f, 0.f);
        if (gi < NUM_ITEMS) {
            int row = items[gi];
            v = *(const float4*)(vtab + row * DIMK + fc * 4);
        }
        float4 w0 = *(const float4*)(wv + fc * 4);
        float4 w1 = *(const float4*)(wc + fc * 4);
        float4 w2 = *(const float4*)(wb + fc * 4);
        ushort4 s;
        s.x = f2bf(v.x * w0.x); s.y = f2bf(v.y * w0.y);
        s.z = f2bf(v.z * w0.z); s.w = f2bf(v.w * w0.w);
        *(ushort4*)(&vt[0][it * VPAD + fc * 4]) = s;
        s.x = f2bf(v.x * w1.x); s.y = f2bf(v.y * w1.y);
        s.z = f2bf(v.z * w1.z); s.w = f2bf(v.w * w1.w);
        *(ushort4*)(&vt[1][it * VPAD + fc * 4]) = s;
        s.x = f2bf(v.x * w2.x); s.y = f2bf(v.y * w2.y);
        s.z = f2bf(v.z * w2.z); s.w = f2bf(v.w * w2.w);
        *(ushort4*)(&vt[2][it * VPAD + fc * 4]) = s;
    }

    // ---- stage u chunk 0 into ut[0] (coalesced float4, f32 -> bf16) ----
    {
        int rowA = users[us];
        int rowB = users[us + 16];
        float4 uA = *(const float4*)(utab + (long)rowA * DIMK + f4 * 4);
        float4 uB = *(const float4*)(utab + (long)rowB * DIMK + f4 * 4);
        ushort4 s;
        s.x = f2bf(uA.x); s.y = f2bf(uA.y); s.z = f2bf(uA.z); s.w = f2bf(uA.w);
        *(ushort4*)(&ut[0][us * UPAD + f4 * 4]) = s;
        s.x = f2bf(uB.x); s.y = f2bf(uB.y); s.z = f2bf(uB.z); s.w = f2bf(uB.w);
        *(ushort4*)(&ut[0][(us + 16) * UPAD + f4 * 4]) = s;
    }
    __syncthreads();   // prologue only; no output stores outstanding yet

    // ---- v fragments in registers: A-operand (m = item = l16, k = quad*8+j) ----
    bfrag_t vfx[3][2];
    #pragma unroll
    for (int x = 0; x < 3; ++x) {
        const unsigned short* vr = &vt[x][(wave * 16 + l16) * VPAD + quad * 8];
        vfx[x][0] = *(const bfrag_t*)(vr);
        vfx[x][1] = *(const bfrag_t*)(vr + 32);
    }

    // D layout (operands swapped): col(n) = l16 = user, row(m) = quad*4 + r = item.
    // Each lane stores a contiguous float4 of 4 items for one user row.
    const int  icol   = iblk + wave * 16 + quad * 4;
    const bool istore = (icol < NUM_ITEMS);    // icol % 4 == 0, 50000 % 4 == 0

    float* p[3][2];
    #pragma unroll
    for (int x = 0; x < 3; ++x)
        #pragma unroll
        for (int s = 0; s < 2; ++s)
            p[x][s] = out + ((long)x * NUM_B + s * 16 + l16) * (long)NUM_ITEMS + icol;

    #pragma unroll 2
    for (int uc = 0; uc < NCHUNK; ++uc) {
        const int cb = uc & 1;

        // ---- issue next chunk's u loads early (latency hides under MFMA+stores) ----
        float4 uA, uB;
        if (uc + 1 < NCHUNK) {
            int rowA = users[(uc + 1) * UC + us];
            int rowB = users[(uc + 1) * UC + us + 16];
            uA = *(const float4*)(utab + (long)rowA * DIMK + f4 * 4);
            uB = *(const float4*)(utab + (long)rowB * DIMK + f4 * 4);
        }

        // ---- B-frags from ut[cb]: n = user = s*16 + l16, k = quad*8 + j ----
        bfrag_t b[2][2];
        #pragma unroll
        for (int s = 0; s < 2; ++s) {
            const unsigned short* ur = &ut[cb][(s * 16 + l16) * UPAD + quad * 8];
            b[s][0] = *(const bfrag_t*)(ur);
            b[s][1] = *(const bfrag_t*)(ur + 32);
        }

        facc_t acc[2][3];
        #pragma unroll
        for (int s = 0; s < 2; ++s)
            #pragma unroll
            for (int x = 0; x < 3; ++x)
                acc[s][x] = (facc_t){0.f, 0.f, 0.f, 0.f};

        #pragma unroll
        for (int s = 0; s < 2; ++s)
            #pragma unroll
            for (int x = 0; x < 3; ++x) {
                acc[s][x] = __builtin_amdgcn_mfma_f32_16x16x32_bf16(vfx[x][0], b[s][0], acc[s][x], 0, 0, 0);
                acc[s][x] = __builtin_amdgcn_mfma_f32_16x16x32_bf16(vfx[x][1], b[s][1], acc[s][x], 0, 0, 0);
            }

        if (istore) {
            #pragma unroll
            for (int x = 0; x < 3; ++x)
                #pragma unroll
                for (int s = 0; s < 2; ++s)
                    __builtin_nontemporal_store(acc[s][x], (facc_t*)p[x][s]);
        }
        #pragma unroll
        for (int x = 0; x < 3; ++x)
            #pragma unroll
            for (int s = 0; s < 2; ++s)
                p[x][s] += (long)UC * NUM_ITEMS;

        // ---- write next chunk into ut[cb^1]; barrier waits LDS only ----
        if (uc + 1 < NCHUNK) {
            ushort4 s;
            s.x = f2bf(uA.x); s.y = f2bf(uA.y); s.z = f2bf(uA.z); s.w = f2bf(uA.w);
            *(ushort4*)(&ut[cb ^ 1][us * UPAD + f4 * 4]) = s;
            s.x = f2bf(uB.x); s.y = f2bf(uB.y); s.z = f2bf(uB.z); s.w = f2bf(uB.w);
            *(ushort4*)(&ut[cb ^ 1][(us + 16) * UPAD + f4 * 4]) = s;

            // my ds_writes (and my ds_reads of ut[cb], consumed by MFMA above)
            // are lgkm-tracked; output stores (vmcnt) stay in flight.
            asm volatile("s_waitcnt lgkmcnt(0)" ::: "memory");
            __builtin_amdgcn_s_barrier();
        }
    }
}

extern "C" void kernel_launch(void* const* d_in, const int* in_sizes, int n_in,
                              void* d_out, int out_size, void* d_ws, size_t ws_size,
                              hipStream_t stream) {
    const int*   users = (const int*)  d_in[0];   // batch_users [1024]
    const int*   items = (const int*)  d_in[1];   // whole_items [50000]
    // d_in[2] = dropout_ration (0) -> identity, ignored
    const float* utab  = (const float*)d_in[3];   // user_table [100000][64]
    const float* vtab  = (const float*)d_in[4];   // item_table [50000][64]
    const float* wv    = (const float*)d_in[5];   // weight_view [64]
    const float* wc    = (const float*)d_in[6];   // weight_cart [64]
    const float* wb    = (const float*)d_in[7];   // weight_buy [64]
    float* out = (float*)d_out;                   // [3][1024][50000]

    const int grid = (NUM_ITEMS + ITILE - 1) / ITILE;   // 782
    gmf_kernel<<<grid, 256, 0, stream>>>(users, items, utab, vtab, wv, wc, wb, out);
}